// Round 18
// baseline (231.449 us; speedup 1.0000x reference)
//
#include <hip/hip_runtime.h>
#include <hip/hip_bf16.h>
#include <hip/hip_fp16.h>
#include <math.h>

#define N_ATOMS  50000
#define N_MOTIFS 50000
#define N_SEG    (N_MOTIFS + N_ATOMS)   // 100000 combined segments
#define N_INC    600000
#define N_GRAPHS 512
#define H        64
#define MOTIF_DIM 94
#define KP       47                     // k-pairs (94/2)
#define HOUT     128
#define BN_EPS   1e-5f
#define NZ       101
#define BCAP     64                     // bucket capacity (Poisson(12); max~35)
#define NBINM    196                    // motif coarse bins (256 segs each)
#define NBIN     392                    // + 196 atom coarse bins
#define BINCAP   4096                   // entries per coarse bin
#define CHUNK    2048                   // edges per bin_scatter block
#define NBLK_S   ((N_INC + CHUNK - 1) / CHUNK)  // 293
#define TL       16                     // motif rows per tile (divides 50000)
#define NBLK_T   (N_MOTIFS / TL)        // 3125 tiles = 3125 blocks (1 tile each)
#define NREP     32                     // BN accumulator replicas
#define LOG2E    1.44269504088896f
#define LN2      0.69314718055995f

typedef _Float16 h2_t __attribute__((ext_vector_type(2)));
typedef float f32x2 __attribute__((ext_vector_type(2)));
__device__ __forceinline__ float fdot2(__half2 a, __half2 b, float c) {
    return __builtin_amdgcn_fdot2(*(h2_t*)&a, *(h2_t*)&b, c, false);
}

__device__ __forceinline__ float softplus_fast(float x) {
    return fmaxf(x, 0.0f) + __logf(1.0f + __expf(-fabsf(x)));
}
// gate in LOG2E-prescaled domain: f',c' = log2e*(f,c). Result needs *LN2 once
// per reduction (softplus scale); sigmoid is scale-free in this form.
__device__ __forceinline__ float gate2(float f, float c) {
    float e   = __builtin_amdgcn_exp2f(-f);
    float sig = __builtin_amdgcn_rcpf(1.0f + e);
    float ec  = __builtin_amdgcn_exp2f(-fabsf(c));
    float sp  = fmaxf(c, 0.0f) + __builtin_amdgcn_logf(1.0f + ec);
    return sig * sp;
}

// FUSED: blocks [0,NBLK_S) = coarse binning with LDS aggregation;
// blocks [NBLK_S, NBLK_S+NZ+1) = aux table builds (independent work, one
// launch saved). All projected tables are LOG2E-prescaled for the exp2 gate.
__global__ __launch_bounds__(256) void bin_scatter_aux(const int* __restrict__ he,
                                                       const int* __restrict__ atom_z,
                                                       unsigned* __restrict__ bin_cnt,
                                                       unsigned* __restrict__ gbin,
                                                       const float* __restrict__ table,
                                                       const float* __restrict__ w_f,
                                                       const float* __restrict__ w_c,
                                                       const float* __restrict__ b_f,
                                                       const float* __restrict__ b_c,
                                                       float* __restrict__ atab_fc,
                                                       __half* __restrict__ ptab_h,
                                                       __half2* __restrict__ w2_fc,
                                                       float* __restrict__ b_fc) {
    __shared__ unsigned ecnt[NBIN];
    __shared__ unsigned ebase[NBIN];
    __shared__ float trow[H];
    int tid = threadIdx.x;
    if (blockIdx.x >= NBLK_S) {   // ---- aux part ----
        int z = blockIdx.x - NBLK_S;
        if (z >= NZ) {   // w2_fc[kp][t]=(W[2H+2kp][col],W[2H+2kp+1][col])*LOG2E
            if (tid < 128) {
                int sel = tid & 1, col = tid >> 1;
                b_fc[tid] = (sel ? b_c : b_f)[col] * LOG2E;
                const float* ws = sel ? w_c : w_f;
                for (int kp = 0; kp < KP; kp++)
                    w2_fc[(size_t)kp * 128 + tid] = __floats2half2_rn(
                        ws[(size_t)(2 * H + 2 * kp) * H + col] * LOG2E,
                        ws[(size_t)(2 * H + 2 * kp + 1) * H + col] * LOG2E);
            }
            return;
        }
        if (tid < H) trow[tid] = table[(size_t)z * H + tid];
        __syncthreads();
        if (tid < 128) {
            int sel = (tid >= 64) ? 1 : 0;
            int jj = tid & 63;
            const float* ws = sel ? w_c : w_f;
            float aacc = 0.0f, pacc = 0.0f;
            for (int k = 0; k < H; k++) {
                float tv = trow[k];
                aacc += tv * ws[(size_t)k * H + jj];
                pacc += tv * ws[(size_t)(H + k) * H + jj];
            }
            atab_fc[(size_t)z * 128 + jj * 2 + sel] = aacc * LOG2E;
            ptab_h[(size_t)z * 128 + jj * 2 + sel] = __float2half_rn(pacc * LOG2E);
        }
        return;
    }
    // ---- bin_scatter part ----
    int e0 = blockIdx.x * CHUNK;
    int e1 = (e0 + CHUNK < N_INC) ? e0 + CHUNK : N_INC;
    for (int i = tid; i < NBIN; i += 256) ecnt[i] = 0;
    __syncthreads();
    for (int e = e0 + tid; e < e1; e += 256) {
        int s = he[e];
        int h = he[N_INC + e];
        atomicAdd(&ecnt[h >> 8], 1u);               // LDS atomic
        atomicAdd(&ecnt[NBINM + (s >> 8)], 1u);     // LDS atomic
    }
    __syncthreads();
    for (int i = tid; i < NBIN; i += 256) {
        unsigned c = ecnt[i];
        ebase[i] = c ? atomicAdd(&bin_cnt[i], c) : 0u;
        ecnt[i] = 0u;                                // reuse as cursor
    }
    __syncthreads();
    for (int e = e0 + tid; e < e1; e += 256) {
        int s = he[e];
        int h = he[N_INC + e];
        int az = atom_z[s];
        int bm = h >> 8;
        unsigned sm = ebase[bm] + atomicAdd(&ecnt[bm], 1u);
        if (sm < BINCAP)
            gbin[(size_t)bm * BINCAP + sm] = ((unsigned)(h & 255) << 16) | (unsigned)az;
        int ba = NBINM + (s >> 8);
        unsigned sa = ebase[ba] + atomicAdd(&ecnt[ba], 1u);
        if (sa < BINCAP)
            gbin[(size_t)ba * BINCAP + sa] = ((unsigned)(s & 255) << 16) | (unsigned)h;
    }
}

// Pass 2: one block per coarse bin; assemble buckets in LDS, write coalesced.
__global__ __launch_bounds__(256) void bin_build(const unsigned* __restrict__ bin_cnt,
                                                 const unsigned* __restrict__ gbin,
                                                 unsigned* __restrict__ cnt,
                                                 unsigned char* __restrict__ csr_m,
                                                 unsigned short* __restrict__ csr_a) {
    __shared__ unsigned short bkt[256 * BCAP];   // 32KB
    __shared__ unsigned cnts[256];
    int b = blockIdx.x;
    int tid = threadIdx.x;
    bool isM = b < NBINM;
    int seg0 = (isM ? b : (b - NBINM)) << 8;
    int lim = 50000 - seg0; if (lim > 256) lim = 256; if (lim < 0) lim = 0;
    cnts[tid] = 0u;
    __syncthreads();
    unsigned n = bin_cnt[b];
    if (n > BINCAP) n = BINCAP;
    for (unsigned k = tid; k < n; k += 256) {
        unsigned e = gbin[(size_t)b * BINCAP + k];
        unsigned loc = e >> 16, val = e & 0xFFFFu;
        unsigned slot = atomicAdd(&cnts[loc], 1u);  // LDS atomic
        if (slot < BCAP) bkt[loc * BCAP + slot] = (unsigned short)val;
    }
    __syncthreads();
    if (tid < lim) cnt[(isM ? seg0 : N_MOTIFS + seg0) + tid] = cnts[tid];
    if (isM) {
        for (int i = tid; i < lim * 16; i += 256) {
            int loc = i >> 4, w = i & 15;
            const unsigned short* sp = &bkt[loc * BCAP + 4 * w];
            unsigned v = (sp[0] & 0xffu) | ((sp[1] & 0xffu) << 8) |
                         ((sp[2] & 0xffu) << 16) | ((sp[3] & 0xffu) << 24);
            ((unsigned*)csr_m)[(size_t)(seg0 + loc) * 16 + w] = v;
        }
    } else {
        for (int i = tid; i < lim * 32; i += 256) {
            int loc = i >> 5, w = i & 31;
            const unsigned short* sp = &bkt[loc * BCAP + 2 * w];
            unsigned v = (unsigned)sp[0] | ((unsigned)sp[1] << 16);
            ((unsigned*)csr_a)[(size_t)(seg0 + loc) * 32 + w] = v;
        }
    }
}

// FUSED motif kernel, ONE TILE PER BLOCK (3125 blocks): W in LDS, ptab fp16
// via L1 (25.9KB < 32KB), nt attr loads. LDS 31.3KB -> 5 resident blocks/CU.
__global__ __launch_bounds__(256) void motif_fused(const unsigned* __restrict__ cnt,
                                                   const unsigned char* __restrict__ csr_m,
                                                   const __half2* __restrict__ ptab_h,
                                                   const float* __restrict__ motif_attr,
                                                   const __half2* __restrict__ w2_fc,
                                                   const float* __restrict__ b_fc,
                                                   __half2* __restrict__ m_fc) {
    __shared__ __half2 w_s[KP * 128];     // 24064B
    __shared__ __half2 z2[TL][KP];        // 3008B
    __shared__ int     ez[TL * BCAP];     // 4096B
    __shared__ float   invd[TL];
    __shared__ int     degs[TL];
    int tid = threadIdx.x;
    int m0 = blockIdx.x * TL;

    for (int k4 = tid; k4 < KP * 32; k4 += 256)
        ((uint4*)w_s)[k4] = ((const uint4*)w2_fc)[k4];
    {   // tile bucket bytes: 16 rows x 64B = 256 ints, 1 per thread
        const int* src = (const int*)(csr_m + (size_t)m0 * BCAP);
        int w = src[tid];
        int b0 = tid * 4;
        ez[b0]     =  w        & 0xff;
        ez[b0 + 1] = (w >> 8)  & 0xff;
        ez[b0 + 2] = (w >> 16) & 0xff;
        ez[b0 + 3] = (w >> 24) & 0xff;
    }
    if (tid < TL) {
        int d = (int)cnt[m0 + tid];
        d = (d < BCAP) ? d : BCAP;
        degs[tid] = d;
        invd[tid] = 1.0f / fmaxf((float)d, 1.0f);
    }
    {   // attr staging, NON-TEMPORAL (don't evict ptab from L1)
        const f32x2* ap = (const f32x2*)motif_attr;
        for (int idx = tid; idx < TL * KP; idx += 256) {
            int m = idx / KP, kp = idx % KP;
            f32x2 v = __builtin_nontemporal_load(&ap[(size_t)(m0 + m) * KP + kp]);
            z2[m][kp] = __floats2half2_rn(v.x, v.y);
        }
    }
    __syncthreads();

    const uint2* ptab_u2 = (const uint2*)ptab_h;   // 32 uint2 per z-row
    int rg = tid >> 5;        // 8 row groups x 2 rows = 16 rows
    int cg = tid & 31;        // 32 col-pair groups
    int q  = cg * 4;          // float col offset in the 128-wide interleaved row
    float4 bias4 = *(const float4*)(b_fc + q);   // (f0,c0,f1,c1)

    float acc[2][4];
#pragma unroll
    for (int i = 0; i < 2; i++) {
        int r = rg * 2 + i;
        int lo = r * BCAP, d = degs[r];
        float g0 = 0.f, g1 = 0.f, g2 = 0.f, g3 = 0.f;
        int k = 0;
        for (; k + 8 <= d; k += 8) {
            int zz[8];
#pragma unroll
            for (int u = 0; u < 8; u++) zz[u] = ez[lo + k + u];
#pragma unroll
            for (int u = 0; u < 8; u++) {
                uint2 pr = ptab_u2[zz[u] * 32 + cg];   // L1-resident row pair
                float2 fa = __half22float2(*(__half2*)&pr.x);
                float2 fb = __half22float2(*(__half2*)&pr.y);
                g0 += fa.x; g1 += fa.y; g2 += fb.x; g3 += fb.y;
            }
        }
        for (; k < d; k++) {
            uint2 pr = ptab_u2[ez[lo + k] * 32 + cg];
            float2 fa = __half22float2(*(__half2*)&pr.x);
            float2 fb = __half22float2(*(__half2*)&pr.y);
            g0 += fa.x; g1 += fa.y; g2 += fb.x; g3 += fb.y;
        }
        float iv = invd[r];
        acc[i][0] = bias4.x + g0 * iv;
        acc[i][1] = bias4.y + g1 * iv;
        acc[i][2] = bias4.z + g2 * iv;
        acc[i][3] = bias4.w + g3 * iv;
    }

    {   // matmul phase: 47 k-pairs x (2 rows x 4 cols) dot2
        int r0 = rg * 2, r1 = r0 + 1;
#pragma unroll 4
        for (int kp = 0; kp < KP; kp++) {
            uint4 wr = *(const uint4*)(w_s + (size_t)kp * 128 + q);
            __half2 w0 = *(__half2*)&wr.x, w1 = *(__half2*)&wr.y;
            __half2 w2h = *(__half2*)&wr.z, w3 = *(__half2*)&wr.w;
            __half2 za = z2[r0][kp], zb = z2[r1][kp];
            acc[0][0] = fdot2(za, w0,  acc[0][0]);
            acc[0][1] = fdot2(za, w1,  acc[0][1]);
            acc[0][2] = fdot2(za, w2h, acc[0][2]);
            acc[0][3] = fdot2(za, w3,  acc[0][3]);
            acc[1][0] = fdot2(zb, w0,  acc[1][0]);
            acc[1][1] = fdot2(zb, w1,  acc[1][1]);
            acc[1][2] = fdot2(zb, w2h, acc[1][2]);
            acc[1][3] = fdot2(zb, w3,  acc[1][3]);
        }
    }
#pragma unroll
    for (int i = 0; i < 2; i++) {
        int gm = m0 + rg * 2 + i;
        m_fc[(size_t)gm * 64 + cg * 2]     = __floats2half2_rn(acc[i][0], acc[i][1]);
        m_fc[(size_t)gm * 64 + cg * 2 + 1] = __floats2half2_rn(acc[i][2], acc[i][3]);
    }
}

// one wave per atom; EXACT-d loads (wave-uniform guards skip clamped slots ->
// ~33% fewer gather rows); exp2-domain gate (prescaled tables, *LN2 once).
__global__ __launch_bounds__(256) void msg_gather(const unsigned* __restrict__ cnt,
                                                  const unsigned short* __restrict__ csr_a,
                                                  const int* __restrict__ atom_z,
                                                  const float2* __restrict__ atab_fc,
                                                  const __half2* __restrict__ m_fc,
                                                  float* __restrict__ out_mean,
                                                  float* __restrict__ bn_part) {
    int i = blockIdx.x * 4 + (threadIdx.x >> 6);
    int j = threadIdx.x & 63;
    int zi = __builtin_amdgcn_readfirstlane(atom_z[i]);   // wave-uniform
    float2 a = atab_fc[(size_t)zi * H + j];
    unsigned b = (unsigned)i * BCAP;
    int d = (int)__builtin_amdgcn_readfirstlane(cnt[N_MOTIFS + i]);
    d = (d < BCAP) ? d : BCAP;
    float acc = 0.0f;
    for (int k = 0; k < d; k += 8) {
        int hh[8];
        __half2 hv[8];
#pragma unroll
        for (int u = 0; u < 8; u++)
            if (k + u < d) hh[u] = (int)csr_a[b + (unsigned)(k + u)];
#pragma unroll
        for (int u = 0; u < 8; u++)
            if (k + u < d) hv[u] = m_fc[((unsigned)hh[u] << 6) + (unsigned)j];
#pragma unroll
        for (int u = 0; u < 8; u++)
            if (k + u < d) {  // wave-uniform: exact load AND gate count
                float2 v = __half22float2(hv[u]);
                acc += gate2(a.x + v.x, a.y + v.y);
            }
    }
    float v = (acc * LN2) / fmaxf((float)d, 1.0f);
    out_mean[(size_t)i * H + j] = v;
    __shared__ float ssum[256];
    __shared__ float ssq[256];
    ssum[threadIdx.x] = v; ssq[threadIdx.x] = v * v;
    __syncthreads();
    if (threadIdx.x < 64) {
        float* rep = bn_part + (size_t)(blockIdx.x & (NREP - 1)) * 128;
        atomicAdd(&rep[j],      ssum[j] + ssum[64 + j] + ssum[128 + j] + ssum[192 + j]);
        atomicAdd(&rep[64 + j], ssq[j]  + ssq[64 + j]  + ssq[128 + j]  + ssq[192 + j]);
    }
}

// one block per graph: reduce BN replicas + bounds search + BN-apply + residual +
// relu + mean-pool, then the MLP head inline.
__global__ __launch_bounds__(256) void pool_head(const float* __restrict__ out_mean,
                                                 const float* __restrict__ bn_part,
                                                 const float* __restrict__ gamma,
                                                 const float* __restrict__ beta,
                                                 const int* __restrict__ atom_z,
                                                 const float* __restrict__ table,
                                                 const int* __restrict__ batch,
                                                 const float* __restrict__ w_l1,
                                                 const float* __restrict__ b_l1,
                                                 const float* __restrict__ w_out,
                                                 const float* __restrict__ b_out,
                                                 float* __restrict__ out) {
    int g = blockIdx.x;
    int tid = threadIdx.x;
    __shared__ int bounds[2];
    __shared__ float red[256];
    __shared__ float gv[H];
    __shared__ float red2[HOUT];
    __shared__ float bnred[128];
    if (tid < 2) {
        int target = g + tid;
        int lo = 0, hi = N_ATOMS;
        while (lo < hi) {
            int mid = (lo + hi) >> 1;
            if (batch[mid] < target) lo = mid + 1; else hi = mid;
        }
        bounds[tid] = lo;
    }
    if (tid < 128) {
        float s = 0.0f;
        for (int r = 0; r < NREP; r++) s += bn_part[(size_t)r * 128 + tid];
        bnred[tid] = s;
    }
    __syncthreads();
    int s = bounds[0], e = bounds[1];
    int j = tid & 63, w = tid >> 6;
    const float invN = 1.0f / (float)N_ATOMS;
    float mu = bnred[j] * invN;
    float var = bnred[64 + j] * invN - mu * mu;
    float rstd = 1.0f / sqrtf(var + BN_EPS);
    float gm = gamma[j], bt = beta[j];
    float acc = 0.0f;
    for (int i = s + w; i < e; i += 4) {
        float d = out_mean[(size_t)i * H + j];
        float xv = table[(size_t)atom_z[i] * H + j];
        float o = (d - mu) * rstd * gm + bt;
        acc += fmaxf(o + xv, 0.0f);
    }
    red[tid] = acc;
    __syncthreads();
    if (tid < 64)
        gv[j] = (red[j] + red[64 + j] + red[128 + j] + red[192 + j])
                / fmaxf((float)(e - s), 1.0f);
    __syncthreads();
    if (tid < HOUT) {
        float a2 = b_l1[tid];
        for (int k = 0; k < H; k++) a2 += gv[k] * w_l1[(size_t)k * HOUT + tid];
        red2[tid] = softplus_fast(a2) * w_out[tid];
    }
    __syncthreads();
    for (int st = 64; st > 0; st >>= 1) {
        if (tid < st) red2[tid] += red2[tid + st];
        __syncthreads();
    }
    if (tid == 0) out[g] = red2[0] + b_out[0];
}

extern "C" void kernel_launch(void* const* d_in, const int* in_sizes, int n_in,
                              void* d_out, int out_size, void* d_ws, size_t ws_size,
                              hipStream_t stream) {
    const int*   atom_z     = (const int*)  d_in[0];
    const float* motif_attr = (const float*)d_in[1];
    const int*   he         = (const int*)  d_in[2];
    const int*   batch      = (const int*)  d_in[3];
    const float* table      = (const float*)d_in[4];
    const float* w_f        = (const float*)d_in[5];
    const float* b_f        = (const float*)d_in[6];
    const float* w_c        = (const float*)d_in[7];
    const float* b_c        = (const float*)d_in[8];
    const float* gamma      = (const float*)d_in[9];
    const float* beta       = (const float*)d_in[10];
    const float* w_l1       = (const float*)d_in[11];
    const float* b_l1       = (const float*)d_in[12];
    const float* w_out      = (const float*)d_in[13];
    const float* b_out      = (const float*)d_in[14];
    float* out = (float*)d_out;

    // ---- workspace layout (16B-aligned) ----
    float*    bn_part = (float*)d_ws;                        // 32*128 (zeroed)
    unsigned* bin_cnt = (unsigned*)(bn_part + NREP * 128);   // 392 -> pad 400 (zeroed)
    char*     zero_end = (char*)(bin_cnt + 400);
    unsigned* cnt     = (unsigned*)zero_end;                 // 100,000 (written by bin_build)
    unsigned* gbin    = cnt + N_SEG;                         // 392*4096 = 6.4MB
    unsigned char*  csr_m = (unsigned char*)(gbin + (size_t)NBIN * BINCAP);  // 3.2MB
    unsigned short* csr_a = (unsigned short*)(csr_m + (size_t)N_MOTIFS * BCAP);  // 6.4MB
    float*    atab_fc  = (float*)(csr_a + (size_t)N_ATOMS * BCAP);   // 101*128 fp32
    __half*   ptab_h   = (__half*)(atab_fc + (size_t)NZ * 128);      // 101*128 fp16 = 25856B
    __half2*  w2_fc    = (__half2*)(ptab_h + (size_t)NZ * 128);      // 47*128 half2 = 24064B
    float*    b_fc     = (float*)(w2_fc + (size_t)KP * 128);         // 128
    __half2*  m_fc     = (__half2*)(b_fc + 128);             // 50,000*64 half2 = 12.8MB
    float*    out_mean = (float*)(m_fc + (size_t)N_MOTIFS * 64);  // 3.2M

    size_t zero_bytes = (size_t)(zero_end - (char*)d_ws);
    hipMemsetAsync(d_ws, 0, zero_bytes, stream);

    bin_scatter_aux<<<NBLK_S + NZ + 1, 256, 0, stream>>>(he, atom_z, bin_cnt, gbin,
                                                         table, w_f, w_c, b_f, b_c,
                                                         atab_fc, ptab_h, w2_fc, b_fc);
    bin_build<<<NBIN, 256, 0, stream>>>(bin_cnt, gbin, cnt, csr_m, csr_a);
    motif_fused<<<NBLK_T, 256, 0, stream>>>(cnt, csr_m, (const __half2*)ptab_h,
                                            motif_attr, w2_fc, b_fc, m_fc);
    msg_gather<<<N_ATOMS / 4, 256, 0, stream>>>(cnt, csr_a, atom_z,
                                                (const float2*)atab_fc,
                                                m_fc, out_mean, bn_part);
    pool_head<<<N_GRAPHS, 256, 0, stream>>>(out_mean, bn_part, gamma, beta,
                                            atom_z, table, batch,
                                            w_l1, b_l1, w_out, b_out, out);
}

// Round 19
// 212.022 us; speedup vs baseline: 1.0916x; 1.0916x over previous
//
#include <hip/hip_runtime.h>
#include <hip/hip_bf16.h>
#include <hip/hip_fp16.h>
#include <math.h>

#define N_ATOMS  50000
#define N_MOTIFS 50000
#define N_SEG    (N_MOTIFS + N_ATOMS)   // 100000 combined segments
#define N_INC    600000
#define N_GRAPHS 512
#define H        64
#define MOTIF_DIM 94
#define KP       47                     // k-pairs (94/2)
#define HOUT     128
#define BN_EPS   1e-5f
#define NZ       101
#define BCAP     64                     // bucket capacity (Poisson(12); max~35)
#define NBINM    196                    // motif coarse bins (256 segs each)
#define NBIN     392                    // + 196 atom coarse bins
#define BINCAP   4096                   // entries per coarse bin
#define CHUNK    2048                   // edges per bin_scatter block
#define NBLK_S   ((N_INC + CHUNK - 1) / CHUNK)  // 293
#define TL       16                     // motif rows per tile (divides 50000)
#define NBLK_T   (N_MOTIFS / TL)        // 3125 tiles = 3125 blocks (1 tile each)
#define NREP     32                     // BN accumulator replicas
#define LOG2E    1.44269504088896f
#define LN2      0.69314718055995f

typedef _Float16 h2_t __attribute__((ext_vector_type(2)));
typedef float f32x2 __attribute__((ext_vector_type(2)));
__device__ __forceinline__ float fdot2(__half2 a, __half2 b, float c) {
    return __builtin_amdgcn_fdot2(*(h2_t*)&a, *(h2_t*)&b, c, false);
}

__device__ __forceinline__ float softplus_fast(float x) {
    return fmaxf(x, 0.0f) + __logf(1.0f + __expf(-fabsf(x)));
}
// gate in LOG2E-prescaled domain: f',c' = log2e*(f,c). Result needs *LN2 once
// per reduction (softplus scale); sigmoid is scale-free in this form.
__device__ __forceinline__ float gate2(float f, float c) {
    float e   = __builtin_amdgcn_exp2f(-f);
    float sig = __builtin_amdgcn_rcpf(1.0f + e);
    float ec  = __builtin_amdgcn_exp2f(-fabsf(c));
    float sp  = fmaxf(c, 0.0f) + __builtin_amdgcn_logf(1.0f + ec);
    return sig * sp;
}

// FUSED: blocks [0,NBLK_S) = coarse binning with LDS aggregation;
// blocks [NBLK_S, NBLK_S+NZ+1) = aux table builds. Tables LOG2E-prescaled.
__global__ __launch_bounds__(256) void bin_scatter_aux(const int* __restrict__ he,
                                                       const int* __restrict__ atom_z,
                                                       unsigned* __restrict__ bin_cnt,
                                                       unsigned* __restrict__ gbin,
                                                       const float* __restrict__ table,
                                                       const float* __restrict__ w_f,
                                                       const float* __restrict__ w_c,
                                                       const float* __restrict__ b_f,
                                                       const float* __restrict__ b_c,
                                                       float* __restrict__ atab_fc,
                                                       __half* __restrict__ ptab_h,
                                                       __half2* __restrict__ w2_fc,
                                                       float* __restrict__ b_fc) {
    __shared__ unsigned ecnt[NBIN];
    __shared__ unsigned ebase[NBIN];
    __shared__ float trow[H];
    int tid = threadIdx.x;
    if (blockIdx.x >= NBLK_S) {   // ---- aux part ----
        int z = blockIdx.x - NBLK_S;
        if (z >= NZ) {   // w2_fc[kp][t]=(W[2H+2kp][col],W[2H+2kp+1][col])*LOG2E
            if (tid < 128) {
                int sel = tid & 1, col = tid >> 1;
                b_fc[tid] = (sel ? b_c : b_f)[col] * LOG2E;
                const float* ws = sel ? w_c : w_f;
                for (int kp = 0; kp < KP; kp++)
                    w2_fc[(size_t)kp * 128 + tid] = __floats2half2_rn(
                        ws[(size_t)(2 * H + 2 * kp) * H + col] * LOG2E,
                        ws[(size_t)(2 * H + 2 * kp + 1) * H + col] * LOG2E);
            }
            return;
        }
        if (tid < H) trow[tid] = table[(size_t)z * H + tid];
        __syncthreads();
        if (tid < 128) {
            int sel = (tid >= 64) ? 1 : 0;
            int jj = tid & 63;
            const float* ws = sel ? w_c : w_f;
            float aacc = 0.0f, pacc = 0.0f;
            for (int k = 0; k < H; k++) {
                float tv = trow[k];
                aacc += tv * ws[(size_t)k * H + jj];
                pacc += tv * ws[(size_t)(H + k) * H + jj];
            }
            atab_fc[(size_t)z * 128 + jj * 2 + sel] = aacc * LOG2E;
            ptab_h[(size_t)z * 128 + jj * 2 + sel] = __float2half_rn(pacc * LOG2E);
        }
        return;
    }
    // ---- bin_scatter part ----
    int e0 = blockIdx.x * CHUNK;
    int e1 = (e0 + CHUNK < N_INC) ? e0 + CHUNK : N_INC;
    for (int i = tid; i < NBIN; i += 256) ecnt[i] = 0;
    __syncthreads();
    for (int e = e0 + tid; e < e1; e += 256) {
        int s = he[e];
        int h = he[N_INC + e];
        atomicAdd(&ecnt[h >> 8], 1u);               // LDS atomic
        atomicAdd(&ecnt[NBINM + (s >> 8)], 1u);     // LDS atomic
    }
    __syncthreads();
    for (int i = tid; i < NBIN; i += 256) {
        unsigned c = ecnt[i];
        ebase[i] = c ? atomicAdd(&bin_cnt[i], c) : 0u;
        ecnt[i] = 0u;                                // reuse as cursor
    }
    __syncthreads();
    for (int e = e0 + tid; e < e1; e += 256) {
        int s = he[e];
        int h = he[N_INC + e];
        int az = atom_z[s];
        int bm = h >> 8;
        unsigned sm = ebase[bm] + atomicAdd(&ecnt[bm], 1u);
        if (sm < BINCAP)
            gbin[(size_t)bm * BINCAP + sm] = ((unsigned)(h & 255) << 16) | (unsigned)az;
        int ba = NBINM + (s >> 8);
        unsigned sa = ebase[ba] + atomicAdd(&ecnt[ba], 1u);
        if (sa < BINCAP)
            gbin[(size_t)ba * BINCAP + sa] = ((unsigned)(s & 255) << 16) | (unsigned)h;
    }
}

// Pass 2: one block per coarse bin; assemble buckets in LDS, write coalesced.
__global__ __launch_bounds__(256) void bin_build(const unsigned* __restrict__ bin_cnt,
                                                 const unsigned* __restrict__ gbin,
                                                 unsigned* __restrict__ cnt,
                                                 unsigned char* __restrict__ csr_m,
                                                 unsigned short* __restrict__ csr_a) {
    __shared__ unsigned short bkt[256 * BCAP];   // 32KB
    __shared__ unsigned cnts[256];
    int b = blockIdx.x;
    int tid = threadIdx.x;
    bool isM = b < NBINM;
    int seg0 = (isM ? b : (b - NBINM)) << 8;
    int lim = 50000 - seg0; if (lim > 256) lim = 256; if (lim < 0) lim = 0;
    cnts[tid] = 0u;
    __syncthreads();
    unsigned n = bin_cnt[b];
    if (n > BINCAP) n = BINCAP;
    for (unsigned k = tid; k < n; k += 256) {
        unsigned e = gbin[(size_t)b * BINCAP + k];
        unsigned loc = e >> 16, val = e & 0xFFFFu;
        unsigned slot = atomicAdd(&cnts[loc], 1u);  // LDS atomic
        if (slot < BCAP) bkt[loc * BCAP + slot] = (unsigned short)val;
    }
    __syncthreads();
    if (tid < lim) cnt[(isM ? seg0 : N_MOTIFS + seg0) + tid] = cnts[tid];
    if (isM) {
        for (int i = tid; i < lim * 16; i += 256) {
            int loc = i >> 4, w = i & 15;
            const unsigned short* sp = &bkt[loc * BCAP + 4 * w];
            unsigned v = (sp[0] & 0xffu) | ((sp[1] & 0xffu) << 8) |
                         ((sp[2] & 0xffu) << 16) | ((sp[3] & 0xffu) << 24);
            ((unsigned*)csr_m)[(size_t)(seg0 + loc) * 16 + w] = v;
        }
    } else {
        for (int i = tid; i < lim * 32; i += 256) {
            int loc = i >> 5, w = i & 31;
            const unsigned short* sp = &bkt[loc * BCAP + 2 * w];
            unsigned v = (unsigned)sp[0] | ((unsigned)sp[1] << 16);
            ((unsigned*)csr_a)[(size_t)(seg0 + loc) * 32 + w] = v;
        }
    }
}

// FUSED motif kernel, ONE TILE PER BLOCK (3125 blocks): W in LDS, ptab fp16
// via L1 (25.9KB < 32KB), nt attr loads. LDS 31.3KB -> 5 resident blocks/CU.
__global__ __launch_bounds__(256) void motif_fused(const unsigned* __restrict__ cnt,
                                                   const unsigned char* __restrict__ csr_m,
                                                   const __half2* __restrict__ ptab_h,
                                                   const float* __restrict__ motif_attr,
                                                   const __half2* __restrict__ w2_fc,
                                                   const float* __restrict__ b_fc,
                                                   __half2* __restrict__ m_fc) {
    __shared__ __half2 w_s[KP * 128];     // 24064B
    __shared__ __half2 z2[TL][KP];        // 3008B
    __shared__ int     ez[TL * BCAP];     // 4096B
    __shared__ float   invd[TL];
    __shared__ int     degs[TL];
    int tid = threadIdx.x;
    int m0 = blockIdx.x * TL;

    for (int k4 = tid; k4 < KP * 32; k4 += 256)
        ((uint4*)w_s)[k4] = ((const uint4*)w2_fc)[k4];
    {   // tile bucket bytes: 16 rows x 64B = 256 ints, 1 per thread
        const int* src = (const int*)(csr_m + (size_t)m0 * BCAP);
        int w = src[tid];
        int b0 = tid * 4;
        ez[b0]     =  w        & 0xff;
        ez[b0 + 1] = (w >> 8)  & 0xff;
        ez[b0 + 2] = (w >> 16) & 0xff;
        ez[b0 + 3] = (w >> 24) & 0xff;
    }
    if (tid < TL) {
        int d = (int)cnt[m0 + tid];
        d = (d < BCAP) ? d : BCAP;
        degs[tid] = d;
        invd[tid] = 1.0f / fmaxf((float)d, 1.0f);
    }
    {   // attr staging, NON-TEMPORAL (don't evict ptab from L1)
        const f32x2* ap = (const f32x2*)motif_attr;
        for (int idx = tid; idx < TL * KP; idx += 256) {
            int m = idx / KP, kp = idx % KP;
            f32x2 v = __builtin_nontemporal_load(&ap[(size_t)(m0 + m) * KP + kp]);
            z2[m][kp] = __floats2half2_rn(v.x, v.y);
        }
    }
    __syncthreads();

    const uint2* ptab_u2 = (const uint2*)ptab_h;   // 32 uint2 per z-row
    int rg = tid >> 5;        // 8 row groups x 2 rows = 16 rows
    int cg = tid & 31;        // 32 col-pair groups
    int q  = cg * 4;          // float col offset in the 128-wide interleaved row
    float4 bias4 = *(const float4*)(b_fc + q);   // (f0,c0,f1,c1)

    float acc[2][4];
#pragma unroll
    for (int i = 0; i < 2; i++) {
        int r = rg * 2 + i;
        int lo = r * BCAP, d = degs[r];
        float g0 = 0.f, g1 = 0.f, g2 = 0.f, g3 = 0.f;
        int k = 0;
        for (; k + 8 <= d; k += 8) {
            int zz[8];
#pragma unroll
            for (int u = 0; u < 8; u++) zz[u] = ez[lo + k + u];
#pragma unroll
            for (int u = 0; u < 8; u++) {
                uint2 pr = ptab_u2[zz[u] * 32 + cg];   // L1-resident row pair
                float2 fa = __half22float2(*(__half2*)&pr.x);
                float2 fb = __half22float2(*(__half2*)&pr.y);
                g0 += fa.x; g1 += fa.y; g2 += fb.x; g3 += fb.y;
            }
        }
        for (; k < d; k++) {
            uint2 pr = ptab_u2[ez[lo + k] * 32 + cg];
            float2 fa = __half22float2(*(__half2*)&pr.x);
            float2 fb = __half22float2(*(__half2*)&pr.y);
            g0 += fa.x; g1 += fa.y; g2 += fb.x; g3 += fb.y;
        }
        float iv = invd[r];
        acc[i][0] = bias4.x + g0 * iv;
        acc[i][1] = bias4.y + g1 * iv;
        acc[i][2] = bias4.z + g2 * iv;
        acc[i][3] = bias4.w + g3 * iv;
    }

    {   // matmul phase: 47 k-pairs x (2 rows x 4 cols) dot2
        int r0 = rg * 2, r1 = r0 + 1;
#pragma unroll 4
        for (int kp = 0; kp < KP; kp++) {
            uint4 wr = *(const uint4*)(w_s + (size_t)kp * 128 + q);
            __half2 w0 = *(__half2*)&wr.x, w1 = *(__half2*)&wr.y;
            __half2 w2h = *(__half2*)&wr.z, w3 = *(__half2*)&wr.w;
            __half2 za = z2[r0][kp], zb = z2[r1][kp];
            acc[0][0] = fdot2(za, w0,  acc[0][0]);
            acc[0][1] = fdot2(za, w1,  acc[0][1]);
            acc[0][2] = fdot2(za, w2h, acc[0][2]);
            acc[0][3] = fdot2(za, w3,  acc[0][3]);
            acc[1][0] = fdot2(zb, w0,  acc[1][0]);
            acc[1][1] = fdot2(zb, w1,  acc[1][1]);
            acc[1][2] = fdot2(zb, w2h, acc[1][2]);
            acc[1][3] = fdot2(zb, w3,  acc[1][3]);
        }
    }
#pragma unroll
    for (int i = 0; i < 2; i++) {
        int gm = m0 + rg * 2 + i;
        m_fc[(size_t)gm * 64 + cg * 2]     = __floats2half2_rn(acc[i][0], acc[i][1]);
        m_fc[(size_t)gm * 64 + cg * 2 + 1] = __floats2half2_rn(acc[i][2], acc[i][3]);
    }
}

// one wave per atom; R12-proven CLAMPED 8-deep load batches (always issued ->
// full pipelining; clamped slots are cache hits, verified free by R17's FETCH);
// wave-uniform guards only on the gate; exp2-domain gate, *LN2 epilogue.
__global__ __launch_bounds__(256) void msg_gather(const unsigned* __restrict__ cnt,
                                                  const unsigned short* __restrict__ csr_a,
                                                  const int* __restrict__ atom_z,
                                                  const float2* __restrict__ atab_fc,
                                                  const __half2* __restrict__ m_fc,
                                                  float* __restrict__ out_mean,
                                                  float* __restrict__ bn_part) {
    int i = blockIdx.x * 4 + (threadIdx.x >> 6);
    int j = threadIdx.x & 63;
    int zi = __builtin_amdgcn_readfirstlane(atom_z[i]);   // wave-uniform
    float2 a = atab_fc[(size_t)zi * H + j];
    unsigned b = (unsigned)i * BCAP;
    int d = (int)__builtin_amdgcn_readfirstlane(cnt[N_MOTIFS + i]);
    d = (d < BCAP) ? d : BCAP;
    int dm1 = (d > 0) ? d - 1 : 0;
    float acc = 0.0f;
    for (int k = 0; k < d; k += 8) {
        int hh[8];
#pragma unroll
        for (int u = 0; u < 8; u++) {
            int o = k + u;
            hh[u] = (int)csr_a[b + (unsigned)((o < d) ? o : dm1)];
        }
        __half2 hv[8];
#pragma unroll
        for (int u = 0; u < 8; u++) hv[u] = m_fc[((unsigned)hh[u] << 6) + (unsigned)j];
#pragma unroll
        for (int u = 0; u < 8; u++)
            if (k + u < d) {  // wave-uniform branch: exact gate count
                float2 v = __half22float2(hv[u]);
                acc += gate2(a.x + v.x, a.y + v.y);
            }
    }
    float v = (acc * LN2) / fmaxf((float)d, 1.0f);
    out_mean[(size_t)i * H + j] = v;
    __shared__ float ssum[256];
    __shared__ float ssq[256];
    ssum[threadIdx.x] = v; ssq[threadIdx.x] = v * v;
    __syncthreads();
    if (threadIdx.x < 64) {
        float* rep = bn_part + (size_t)(blockIdx.x & (NREP - 1)) * 128;
        atomicAdd(&rep[j],      ssum[j] + ssum[64 + j] + ssum[128 + j] + ssum[192 + j]);
        atomicAdd(&rep[64 + j], ssq[j]  + ssq[64 + j]  + ssq[128 + j]  + ssq[192 + j]);
    }
}

// one block per graph: reduce BN replicas + bounds search + BN-apply + residual +
// relu + mean-pool, then the MLP head inline.
__global__ __launch_bounds__(256) void pool_head(const float* __restrict__ out_mean,
                                                 const float* __restrict__ bn_part,
                                                 const float* __restrict__ gamma,
                                                 const float* __restrict__ beta,
                                                 const int* __restrict__ atom_z,
                                                 const float* __restrict__ table,
                                                 const int* __restrict__ batch,
                                                 const float* __restrict__ w_l1,
                                                 const float* __restrict__ b_l1,
                                                 const float* __restrict__ w_out,
                                                 const float* __restrict__ b_out,
                                                 float* __restrict__ out) {
    int g = blockIdx.x;
    int tid = threadIdx.x;
    __shared__ int bounds[2];
    __shared__ float red[256];
    __shared__ float gv[H];
    __shared__ float red2[HOUT];
    __shared__ float bnred[128];
    if (tid < 2) {
        int target = g + tid;
        int lo = 0, hi = N_ATOMS;
        while (lo < hi) {
            int mid = (lo + hi) >> 1;
            if (batch[mid] < target) lo = mid + 1; else hi = mid;
        }
        bounds[tid] = lo;
    }
    if (tid < 128) {
        float s = 0.0f;
        for (int r = 0; r < NREP; r++) s += bn_part[(size_t)r * 128 + tid];
        bnred[tid] = s;
    }
    __syncthreads();
    int s = bounds[0], e = bounds[1];
    int j = tid & 63, w = tid >> 6;
    const float invN = 1.0f / (float)N_ATOMS;
    float mu = bnred[j] * invN;
    float var = bnred[64 + j] * invN - mu * mu;
    float rstd = 1.0f / sqrtf(var + BN_EPS);
    float gm = gamma[j], bt = beta[j];
    float acc = 0.0f;
    for (int i = s + w; i < e; i += 4) {
        float d = out_mean[(size_t)i * H + j];
        float xv = table[(size_t)atom_z[i] * H + j];
        float o = (d - mu) * rstd * gm + bt;
        acc += fmaxf(o + xv, 0.0f);
    }
    red[tid] = acc;
    __syncthreads();
    if (tid < 64)
        gv[j] = (red[j] + red[64 + j] + red[128 + j] + red[192 + j])
                / fmaxf((float)(e - s), 1.0f);
    __syncthreads();
    if (tid < HOUT) {
        float a2 = b_l1[tid];
        for (int k = 0; k < H; k++) a2 += gv[k] * w_l1[(size_t)k * HOUT + tid];
        red2[tid] = softplus_fast(a2) * w_out[tid];
    }
    __syncthreads();
    for (int st = 64; st > 0; st >>= 1) {
        if (tid < st) red2[tid] += red2[tid + st];
        __syncthreads();
    }
    if (tid == 0) out[g] = red2[0] + b_out[0];
}

extern "C" void kernel_launch(void* const* d_in, const int* in_sizes, int n_in,
                              void* d_out, int out_size, void* d_ws, size_t ws_size,
                              hipStream_t stream) {
    const int*   atom_z     = (const int*)  d_in[0];
    const float* motif_attr = (const float*)d_in[1];
    const int*   he         = (const int*)  d_in[2];
    const int*   batch      = (const int*)  d_in[3];
    const float* table      = (const float*)d_in[4];
    const float* w_f        = (const float*)d_in[5];
    const float* b_f        = (const float*)d_in[6];
    const float* w_c        = (const float*)d_in[7];
    const float* b_c        = (const float*)d_in[8];
    const float* gamma      = (const float*)d_in[9];
    const float* beta       = (const float*)d_in[10];
    const float* w_l1       = (const float*)d_in[11];
    const float* b_l1       = (const float*)d_in[12];
    const float* w_out      = (const float*)d_in[13];
    const float* b_out      = (const float*)d_in[14];
    float* out = (float*)d_out;

    // ---- workspace layout (16B-aligned) ----
    float*    bn_part = (float*)d_ws;                        // 32*128 (zeroed)
    unsigned* bin_cnt = (unsigned*)(bn_part + NREP * 128);   // 392 -> pad 400 (zeroed)
    char*     zero_end = (char*)(bin_cnt + 400);
    unsigned* cnt     = (unsigned*)zero_end;                 // 100,000 (written by bin_build)
    unsigned* gbin    = cnt + N_SEG;                         // 392*4096 = 6.4MB
    unsigned char*  csr_m = (unsigned char*)(gbin + (size_t)NBIN * BINCAP);  // 3.2MB
    unsigned short* csr_a = (unsigned short*)(csr_m + (size_t)N_MOTIFS * BCAP);  // 6.4MB
    float*    atab_fc  = (float*)(csr_a + (size_t)N_ATOMS * BCAP);   // 101*128 fp32
    __half*   ptab_h   = (__half*)(atab_fc + (size_t)NZ * 128);      // 101*128 fp16 = 25856B
    __half2*  w2_fc    = (__half2*)(ptab_h + (size_t)NZ * 128);      // 47*128 half2 = 24064B
    float*    b_fc     = (float*)(w2_fc + (size_t)KP * 128);         // 128
    __half2*  m_fc     = (__half2*)(b_fc + 128);             // 50,000*64 half2 = 12.8MB
    float*    out_mean = (float*)(m_fc + (size_t)N_MOTIFS * 64);  // 3.2M

    size_t zero_bytes = (size_t)(zero_end - (char*)d_ws);
    hipMemsetAsync(d_ws, 0, zero_bytes, stream);

    bin_scatter_aux<<<NBLK_S + NZ + 1, 256, 0, stream>>>(he, atom_z, bin_cnt, gbin,
                                                         table, w_f, w_c, b_f, b_c,
                                                         atab_fc, ptab_h, w2_fc, b_fc);
    bin_build<<<NBIN, 256, 0, stream>>>(bin_cnt, gbin, cnt, csr_m, csr_a);
    motif_fused<<<NBLK_T, 256, 0, stream>>>(cnt, csr_m, (const __half2*)ptab_h,
                                            motif_attr, w2_fc, b_fc, m_fc);
    msg_gather<<<N_ATOMS / 4, 256, 0, stream>>>(cnt, csr_a, atom_z,
                                                (const float2*)atab_fc,
                                                m_fc, out_mean, bn_part);
    pool_head<<<N_GRAPHS, 256, 0, stream>>>(out_mean, bn_part, gamma, beta,
                                            atom_z, table, batch,
                                            w_l1, b_l1, w_out, b_out, out);
}